// Round 3
// baseline (421.098 us; speedup 1.0000x reference)
//
#include <hip/hip_runtime.h>
#include <hip/hip_bf16.h>
#include <stdint.h>

#define HIDDEN 1024
#define TOKENS 32768
#define NE 8

typedef unsigned short u16;
typedef short bf16x8 __attribute__((ext_vector_type(8)));
typedef float f32x4 __attribute__((ext_vector_type(4)));

__device__ __forceinline__ void gload_lds16(const void* g, void* l) {
  __builtin_amdgcn_global_load_lds(
      (const __attribute__((address_space(1))) void*)g,
      (__attribute__((address_space(3))) void*)l, 16, 0, 0);
}

// ---------------- K0: expert_weight [h][d] fp32 -> Bt [d][h] bf16 (transpose+convert)
__global__ __launch_bounds__(256) void k0_transpose(const float* __restrict__ B,
                                                    u16* __restrict__ Bt) {
  __shared__ float tile[64][65];
  const int d0 = blockIdx.x * 64;
  const int h0 = blockIdx.y * 64;
  const int t = threadIdx.x;
#pragma unroll
  for (int p = 0; p < 16; ++p) {
    int idx = p * 256 + t;
    int r = idx >> 6, c = idx & 63;
    tile[r][c] = B[(size_t)(h0 + r) * HIDDEN + d0 + c];
  }
  __syncthreads();
#pragma unroll
  for (int p = 0; p < 16; ++p) {
    int idx = p * 256 + t;
    int r = idx >> 6, c = idx & 63;
    __hip_bfloat16 v = __float2bfloat16(tile[c][r]);
    Bt[(size_t)(d0 + r) * HIDDEN + h0 + c] = *(u16*)&v;
  }
}

// ---------------- K1: fp32 gating -> s[tok]; emit A bf16. Gate weights in LDS.
__global__ __launch_bounds__(512) void k1_gate(const float* __restrict__ H,
                                               const float* __restrict__ G,
                                               float* __restrict__ s,
                                               u16* __restrict__ Abf) {
  __shared__ float Gs[NE * HIDDEN];  // 32 KiB
  const int t = threadIdx.x;
#pragma unroll
  for (int i = 0; i < 4; ++i)
    ((float4*)Gs)[i * 512 + t] = ((const float4*)G)[i * 512 + t];
  __syncthreads();

  const int lane = t & 63;
  const int wave = t >> 6;
  const int gw = blockIdx.x * 8 + wave;
  const int tok0 = gw * 4;

#pragma unroll
  for (int tp = 0; tp < 2; ++tp) {
    const int tok = tok0 + tp * 2;
    const float* h0p = H + (size_t)tok * HIDDEN;
    const float* h1p = h0p + HIDDEN;
    float4 h0[4], h1[4];
#pragma unroll
    for (int p = 0; p < 4; ++p) {
      h0[p] = *(const float4*)(h0p + p * 256 + lane * 4);
      h1[p] = *(const float4*)(h1p + p * 256 + lane * 4);
    }
#pragma unroll
    for (int p = 0; p < 4; ++p) {
      __hip_bfloat162 lo0 = __float22bfloat162_rn(make_float2(h0[p].x, h0[p].y));
      __hip_bfloat162 hi0 = __float22bfloat162_rn(make_float2(h0[p].z, h0[p].w));
      uint2 pk0;
      pk0.x = *(unsigned*)&lo0;
      pk0.y = *(unsigned*)&hi0;
      *(uint2*)(Abf + (size_t)tok * HIDDEN + p * 256 + lane * 4) = pk0;
      __hip_bfloat162 lo1 = __float22bfloat162_rn(make_float2(h1[p].x, h1[p].y));
      __hip_bfloat162 hi1 = __float22bfloat162_rn(make_float2(h1[p].z, h1[p].w));
      uint2 pk1;
      pk1.x = *(unsigned*)&lo1;
      pk1.y = *(unsigned*)&hi1;
      *(uint2*)(Abf + (size_t)(tok + 1) * HIDDEN + p * 256 + lane * 4) = pk1;
    }

    float a0[NE], a1[NE];
#pragma unroll
    for (int e = 0; e < NE; ++e) { a0[e] = 0.f; a1[e] = 0.f; }
#pragma unroll
    for (int p = 0; p < 4; ++p)
#pragma unroll
      for (int e = 0; e < NE; ++e) {
        float4 w = *(const float4*)&Gs[e * HIDDEN + p * 256 + lane * 4];
        a0[e] += h0[p].x * w.x + h0[p].y * w.y + h0[p].z * w.z + h0[p].w * w.w;
        a1[e] += h1[p].x * w.x + h1[p].y * w.y + h1[p].z * w.z + h1[p].w * w.w;
      }
#pragma unroll
    for (int st = 1; st <= 4; st <<= 1)
#pragma unroll
      for (int e = 0; e < NE; ++e) {
        a0[e] += __shfl_xor(a0[e], st, 64);
        a1[e] += __shfl_xor(a1[e], st, 64);
      }
    const bool b0 = lane & 1, b1 = lane & 2, b2 = lane & 4;
    float t01 = b0 ? a0[1] : a0[0], t23 = b0 ? a0[3] : a0[2];
    float t45 = b0 ? a0[5] : a0[4], t67 = b0 ? a0[7] : a0[6];
    float u03 = b1 ? t23 : t01, u47 = b1 ? t67 : t45;
    float v0 = b2 ? u47 : u03;
    float s01 = b0 ? a1[1] : a1[0], s23 = b0 ? a1[3] : a1[2];
    float s45 = b0 ? a1[5] : a1[4], s67 = b0 ? a1[7] : a1[6];
    float w03 = b1 ? s23 : s01, w47 = b1 ? s67 : s45;
    float v1 = b2 ? w47 : w03;
    v0 += __shfl_xor(v0, 8, 64);
    v0 += __shfl_xor(v0, 16, 64);
    v0 += __shfl_xor(v0, 32, 64);
    v1 += __shfl_xor(v1, 8, 64);
    v1 += __shfl_xor(v1, 16, 64);
    v1 += __shfl_xor(v1, 32, 64);
    float m1a = v0, m2a = -3.0e38f, m1b = v1, m2b = -3.0e38f;
#pragma unroll
    for (int st = 1; st <= 4; st <<= 1) {
      float o1 = __shfl_xor(m1a, st, 64);
      float o2 = __shfl_xor(m2a, st, 64);
      float lo = fminf(m1a, o1);
      m1a = fmaxf(m1a, o1);
      m2a = fmaxf(lo, fmaxf(m2a, o2));
      float p1 = __shfl_xor(m1b, st, 64);
      float p2 = __shfl_xor(m2b, st, 64);
      float lo2 = fminf(m1b, p1);
      m1b = fmaxf(m1b, p1);
      m2b = fmaxf(lo2, fmaxf(m2b, p2));
    }
    if (lane == 0) {
      s[tok] = m1a + m2a;
      s[tok + 1] = m1b + m2b;
    }
  }
}

// ---------------- K2: fused GEMM + scale + LayerNorm, writes final out.
// Block = 64 rows x 1024 cols (full row -> LN in-block, C buffer eliminated).
// 8 waves, wave tile 64x128 (acc[4][8]); LDS per buf: A x2 replicas (8KiB) + B (64KiB);
// double-buffered = 144 KiB, 1 block/CU. Frag prefetch: tile t+1 ds_reads issued
// before tile t's register-only MFMA cluster; counted vmcnt(9) keeps tile t+3's
// global loads in flight across barriers.
#define BUFE 36864  // u16 elems per buffer (72 KiB)

__global__ __launch_bounds__(512, 2) void k2_fused(const u16* __restrict__ A,
                                                   const u16* __restrict__ Bt,
                                                   const float* __restrict__ s,
                                                   const float* __restrict__ gamma,
                                                   const float* __restrict__ beta,
                                                   float* __restrict__ out) {
  __shared__ u16 smem[2 * BUFE];  // 144 KiB
  const int t = threadIdx.x;
  const int lane = t & 63;
  const int wave = t >> 6;
  const int m0 = blockIdx.x * 64;
  const int wn = wave * 128;
  const int lm = lane & 15;
  const int lq = lane >> 4;

  // ---- staging maps: 9 chunks/thread (uniform -> clean per-wave vmcnt counts)
  // chunk c = t + i*512; i==0 -> A (2 replicas of 64x32), i>=1 -> B row cb = c-512.
  // LDS slot (r,qs) holds global k-chunk q = qs ^ sw(r), sw(r)=(r^(r>>2))&3; LDS
  // dest stays linear (lane*16B) so global_load_lds is legal; swizzle moved to src.
  int aoff;
  {
    int ca = t & 255, r = ca >> 2, qs = t & 3;
    int q = qs ^ ((r ^ (r >> 2)) & 3);
    aoff = (m0 + r) * HIDDEN + q * 8;
  }
  int boff[8];
#pragma unroll
  for (int i = 0; i < 8; ++i) {
    int cb = t + i * 512, r = cb >> 2, qs = cb & 3;
    int q = qs ^ ((r ^ (r >> 2)) & 3);
    boff[i] = r * HIDDEN + q * 8;
  }
  const int dstb = t * 8;  // elem; chunk i at dstb + i*4096

#define STAGE2(buf, kt)                                                       \
  do {                                                                        \
    u16* bs_ = smem + (buf) * BUFE;                                           \
    gload_lds16(A + aoff + (kt) * 32, bs_ + dstb);                            \
    _Pragma("unroll") for (int i_ = 0; i_ < 8; ++i_)                          \
        gload_lds16(Bt + boff[i_] + (kt) * 32, bs_ + dstb + (i_ + 1) * 4096); \
  } while (0)

  // ---- frag read offsets (sw depends only on lm since row%16==lm)
  const int sl = lq ^ ((lm ^ (lm >> 2)) & 3);
  int aro[4], bro[8];
#pragma unroll
  for (int i = 0; i < 4; ++i)
    aro[i] = (wave & 1) * 2048 + (i * 16 + lm) * 32 + sl * 8;
#pragma unroll
  for (int j = 0; j < 8; ++j)
    bro[j] = 4096 + (wn + j * 16 + lm) * 32 + sl * 8;

  f32x4 acc[4][8];
#pragma unroll
  for (int i = 0; i < 4; ++i)
#pragma unroll
    for (int j = 0; j < 8; ++j) acc[i][j] = (f32x4){0.f, 0.f, 0.f, 0.f};

  bf16x8 fa[4], fb[8], ga[4], gb[8];

  // ---- prologue: t0->buf0, t1->buf1; frags(t0) to regs; t2->buf0 in flight
  STAGE2(0, 0);
  STAGE2(1, 1);
  asm volatile("s_waitcnt vmcnt(9)" ::: "memory");
  asm volatile("s_barrier" ::: "memory");
#pragma unroll
  for (int i = 0; i < 4; ++i) fa[i] = *(const bf16x8*)&smem[aro[i]];
#pragma unroll
  for (int j = 0; j < 8; ++j) fb[j] = *(const bf16x8*)&smem[bro[j]];
  asm volatile("s_waitcnt lgkmcnt(0) vmcnt(0)" ::: "memory");
  asm volatile("s_barrier" ::: "memory");
  STAGE2(0, 2);

#define BODY(TT, INA, INB, OUTA, OUTB)                                        \
  do {                                                                        \
    if ((TT) + 1 < 32) {                                                      \
      const u16* fb_ = smem + (((TT) + 1) & 1) * BUFE;                        \
      _Pragma("unroll") for (int i_ = 0; i_ < 4; ++i_)                        \
          OUTA[i_] = *(const bf16x8*)&fb_[aro[i_]];                           \
      _Pragma("unroll") for (int j_ = 0; j_ < 8; ++j_)                        \
          OUTB[j_] = *(const bf16x8*)&fb_[bro[j_]];                           \
    }                                                                         \
    __builtin_amdgcn_s_setprio(1);                                            \
    _Pragma("unroll") for (int j_ = 0; j_ < 8; ++j_)                          \
      _Pragma("unroll") for (int i_ = 0; i_ < 4; ++i_)                        \
          acc[i_][j_] = __builtin_amdgcn_mfma_f32_16x16x32_bf16(              \
              INA[i_], INB[j_], acc[i_][j_], 0, 0, 0);                        \
    __builtin_amdgcn_s_setprio(0);                                            \
    asm volatile("s_waitcnt lgkmcnt(0)" ::: "memory");                        \
    asm volatile("s_barrier" ::: "memory");                                   \
    if ((TT) + 3 < 32) {                                                      \
      STAGE2((((TT) + 1) & 1), (TT) + 3);                                     \
      asm volatile("s_waitcnt vmcnt(9)" ::: "memory");                        \
    } else {                                                                  \
      asm volatile("s_waitcnt vmcnt(0)" ::: "memory");                        \
    }                                                                         \
    asm volatile("s_barrier" ::: "memory");                                   \
  } while (0)

  for (int tt = 0; tt < 32; tt += 2) {
    BODY(tt, fa, fb, ga, gb);
    BODY(tt + 1, ga, gb, fa, fb);
  }
#undef BODY
#undef STAGE2

  // ---- fused epilogue: x = s[row]*acc; LayerNorm over full 1024-wide rows.
  float* S = (float*)smem;          // [64][8][2] partial (sum, sumsq)
  float* R = (float*)smem + 1024;   // [64][2] (mean, rstd)

#pragma unroll
  for (int i = 0; i < 4; ++i) {
#pragma unroll
    for (int r = 0; r < 4; ++r) {
      int row = i * 16 + lq * 4 + r;
      float scv = s[m0 + row];
      float ps = 0.f, pq = 0.f;
#pragma unroll
      for (int j = 0; j < 8; ++j) {
        float v = acc[i][j][r] * scv;
        acc[i][j][r] = v;
        ps += v;
        pq += v * v;
      }
#pragma unroll
      for (int off = 1; off <= 8; off <<= 1) {
        ps += __shfl_xor(ps, off, 64);
        pq += __shfl_xor(pq, off, 64);
      }
      if (lm == 0) {
        S[(row * 8 + wave) * 2] = ps;
        S[(row * 8 + wave) * 2 + 1] = pq;
      }
    }
  }
  __syncthreads();
  if (t < 64) {
    float ssum = 0.f, ssq = 0.f;
#pragma unroll
    for (int w = 0; w < 8; ++w) {
      ssum += S[(t * 8 + w) * 2];
      ssq += S[(t * 8 + w) * 2 + 1];
    }
    float mean = ssum * (1.f / HIDDEN);
    float var = ssq * (1.f / HIDDEN) - mean * mean;
    R[t * 2] = mean;
    R[t * 2 + 1] = rsqrtf(var + 1e-5f);
  }
  __syncthreads();
  float gj[8], bj[8];
#pragma unroll
  for (int j = 0; j < 8; ++j) {
    gj[j] = gamma[wn + j * 16 + lm];
    bj[j] = beta[wn + j * 16 + lm];
  }
#pragma unroll
  for (int i = 0; i < 4; ++i) {
#pragma unroll
    for (int r = 0; r < 4; ++r) {
      int row = i * 16 + lq * 4 + r;
      float mean = R[row * 2];
      float rstd = R[row * 2 + 1];
      float* op = out + (size_t)(m0 + row) * HIDDEN + wn + lm;
#pragma unroll
      for (int j = 0; j < 8; ++j)
        op[j * 16] = (acc[i][j][r] - mean) * rstd * gj[j] + bj[j];
    }
  }
}

extern "C" void kernel_launch(void* const* d_in, const int* in_sizes, int n_in,
                              void* d_out, int out_size, void* d_ws, size_t ws_size,
                              hipStream_t stream) {
  (void)in_sizes; (void)n_in; (void)out_size; (void)ws_size;
  const float* H = (const float*)d_in[0];      // [4,8192,1024] fp32
  const float* G = (const float*)d_in[1];      // [8,1024] fp32
  const float* W = (const float*)d_in[2];      // [1024,1024] fp32
  const float* gamma = (const float*)d_in[3];  // [1024]
  const float* beta = (const float*)d_in[4];   // [1024]
  float* out = (float*)d_out;

  char* ws = (char*)d_ws;
  u16* Bt = (u16*)ws;                                          // 2 MiB
  float* s = (float*)(ws + (size_t)(2u << 20));                // 128 KiB
  u16* Abf = (u16*)(ws + (size_t)(2u << 20) + (256u << 10));   // 64 MiB (old C slot)

  k0_transpose<<<dim3(16, 16), 256, 0, stream>>>(W, Bt);
  k1_gate<<<1024, 512, 0, stream>>>(H, G, s, Abf);
  k2_fused<<<TOKENS / 64, 512, 0, stream>>>(Abf, Bt, s, gamma, beta, out);
}

// Round 4
// 385.117 us; speedup vs baseline: 1.0934x; 1.0934x over previous
//
#include <hip/hip_runtime.h>
#include <hip/hip_bf16.h>
#include <stdint.h>

#define HIDDEN 1024
#define TOKENS 32768
#define NE 8

typedef unsigned short u16;
typedef short bf16x8 __attribute__((ext_vector_type(8)));
typedef float f32x4 __attribute__((ext_vector_type(4)));
typedef unsigned u32x4 __attribute__((ext_vector_type(4)));

__device__ __forceinline__ void gload_lds16(const void* g, void* l) {
  __builtin_amdgcn_global_load_lds(
      (const __attribute__((address_space(1))) void*)g,
      (__attribute__((address_space(3))) void*)l, 16, 0, 0);
}

__device__ __forceinline__ unsigned pkbf(float a, float b) {
  __hip_bfloat162 h = __float22bfloat162_rn(make_float2(a, b));
  return *(unsigned*)&h;
}

// ---------------- K0: expert_weight [h][d] fp32 -> Bt [d][h] bf16 (transpose+convert)
__global__ __launch_bounds__(256) void k0_transpose(const float* __restrict__ B,
                                                    u16* __restrict__ Bt) {
  __shared__ float tile[64][65];
  const int d0 = blockIdx.x * 64;
  const int h0 = blockIdx.y * 64;
  const int t = threadIdx.x;
#pragma unroll
  for (int p = 0; p < 16; ++p) {
    int idx = p * 256 + t;
    int r = idx >> 6, c = idx & 63;
    tile[r][c] = B[(size_t)(h0 + r) * HIDDEN + d0 + c];
  }
  __syncthreads();
#pragma unroll
  for (int p = 0; p < 16; ++p) {
    int idx = p * 256 + t;
    int r = idx >> 6, c = idx & 63;
    __hip_bfloat16 v = __float2bfloat16(tile[c][r]);
    Bt[(size_t)(d0 + r) * HIDDEN + h0 + c] = *(u16*)&v;
  }
}

// ---------------- K1: gating only (fp32): s[tok] = sum of top-2 logits.
// Abf write removed -- k2 now reads H directly. Pure read stream of H.
__global__ __launch_bounds__(512) void k1_gate(const float* __restrict__ H,
                                               const float* __restrict__ G,
                                               float* __restrict__ s) {
  __shared__ float Gs[NE * HIDDEN];  // 32 KiB
  const int t = threadIdx.x;
#pragma unroll
  for (int i = 0; i < 4; ++i)
    ((float4*)Gs)[i * 512 + t] = ((const float4*)G)[i * 512 + t];
  __syncthreads();

  const int lane = t & 63;
  const int wave = t >> 6;
  const int gw = blockIdx.x * 8 + wave;
  const int tok0 = gw * 4;

#pragma unroll
  for (int tp = 0; tp < 2; ++tp) {
    const int tok = tok0 + tp * 2;
    const float* h0p = H + (size_t)tok * HIDDEN;
    const float* h1p = h0p + HIDDEN;
    float4 h0[4], h1[4];
#pragma unroll
    for (int p = 0; p < 4; ++p) {
      h0[p] = *(const float4*)(h0p + p * 256 + lane * 4);
      h1[p] = *(const float4*)(h1p + p * 256 + lane * 4);
    }
    float a0[NE], a1[NE];
#pragma unroll
    for (int e = 0; e < NE; ++e) { a0[e] = 0.f; a1[e] = 0.f; }
#pragma unroll
    for (int p = 0; p < 4; ++p)
#pragma unroll
      for (int e = 0; e < NE; ++e) {
        float4 w = *(const float4*)&Gs[e * HIDDEN + p * 256 + lane * 4];
        a0[e] += h0[p].x * w.x + h0[p].y * w.y + h0[p].z * w.z + h0[p].w * w.w;
        a1[e] += h1[p].x * w.x + h1[p].y * w.y + h1[p].z * w.z + h1[p].w * w.w;
      }
#pragma unroll
    for (int st = 1; st <= 4; st <<= 1)
#pragma unroll
      for (int e = 0; e < NE; ++e) {
        a0[e] += __shfl_xor(a0[e], st, 64);
        a1[e] += __shfl_xor(a1[e], st, 64);
      }
    const bool b0 = lane & 1, b1 = lane & 2, b2 = lane & 4;
    float t01 = b0 ? a0[1] : a0[0], t23 = b0 ? a0[3] : a0[2];
    float t45 = b0 ? a0[5] : a0[4], t67 = b0 ? a0[7] : a0[6];
    float u03 = b1 ? t23 : t01, u47 = b1 ? t67 : t45;
    float v0 = b2 ? u47 : u03;
    float s01 = b0 ? a1[1] : a1[0], s23 = b0 ? a1[3] : a1[2];
    float s45 = b0 ? a1[5] : a1[4], s67 = b0 ? a1[7] : a1[6];
    float w03 = b1 ? s23 : s01, w47 = b1 ? s67 : s45;
    float v1 = b2 ? w47 : w03;
    v0 += __shfl_xor(v0, 8, 64);
    v0 += __shfl_xor(v0, 16, 64);
    v0 += __shfl_xor(v0, 32, 64);
    v1 += __shfl_xor(v1, 8, 64);
    v1 += __shfl_xor(v1, 16, 64);
    v1 += __shfl_xor(v1, 32, 64);
    float m1a = v0, m2a = -3.0e38f, m1b = v1, m2b = -3.0e38f;
#pragma unroll
    for (int st = 1; st <= 4; st <<= 1) {
      float o1 = __shfl_xor(m1a, st, 64);
      float o2 = __shfl_xor(m2a, st, 64);
      float lo = fminf(m1a, o1);
      m1a = fmaxf(m1a, o1);
      m2a = fmaxf(lo, fmaxf(m2a, o2));
      float p1 = __shfl_xor(m1b, st, 64);
      float p2 = __shfl_xor(m2b, st, 64);
      float lo2 = fminf(m1b, p1);
      m1b = fmaxf(m1b, p1);
      m2b = fmaxf(lo2, fmaxf(m2b, p2));
    }
    if (lane == 0) {
      s[tok] = m1a + m2a;
      s[tok + 1] = m1b + m2b;
    }
  }
}

// ---------------- K2: C[m][n] = sum_k A[m][k]*Bt[n][k], bf16 MFMA.
// 256x256 tile, BK=32, 8 waves (2M x 4N). A comes straight from H (fp32):
// reg-load -> cvt bf16 -> ds_write into the swizzled LDS layout (kills the Abf
// round-trip). B stays on global_load_lds. ONE barrier per K-step:
// frag-reads -> MFMA -> lgkmcnt(0)+vmcnt(4) -> s_barrier -> stage(t+2).
__global__ __launch_bounds__(512, 2) void k2_gemm(const float* __restrict__ H,
                                                  const u16* __restrict__ Bt,
                                                  u16* __restrict__ C) {
  __shared__ u16 smem[2 * 2 * 8192];  // [buf][A|B][8192 u16] = 64 KiB
  const int t = threadIdx.x;
  const int lane = t & 63;
  const int wave = t >> 6;

  const int b = blockIdx.x;
  const int tile = (b & 7) * 64 + (b >> 3);
  const int m0 = (tile >> 2) * 256;
  const int n0 = (tile & 3) * 256;

  const int wm = (wave >> 2) * 128;
  const int wn = (wave & 3) * 64;
  const int lm = lane & 15;
  const int lq = lane >> 4;

  // ---- B staging map (global_load_lds; chunk-swizzled source, linear dest)
  const int r0 = t >> 2, r1 = (512 + t) >> 2;
  const int q0 = (t & 3) ^ ((r0 ^ (r0 >> 2)) & 3);
  const int q1 = (t & 3) ^ ((r1 ^ (r1 >> 2)) & 3);
  const u16* gB0 = Bt + (size_t)(n0 + r0) * HIDDEN + q0 * 8;
  const u16* gB1 = Bt + (size_t)(n0 + r1) * HIDDEN + q1 * 8;

  // ---- A reg-staging map: thread t -> row ar = t>>1, 16 k-elems at (t&1)*16.
  // chunks q0a=(t&1)*2, q0a+1 -> LDS slots (q^sw(ar)), adjacent pair.
  const int ar = t >> 1;
  const int asw = (ar ^ (ar >> 2)) & 3;
  const int aslot0 = ((t & 1) * 2) ^ asw;
  const int awr = ar * 32;  // elem base of row in A region
  const float4* gH4 = (const float4*)(H + (size_t)(m0 + ar) * HIDDEN + (t & 1) * 16);

#define STAGE_B(buf, kt)                                             \
  do {                                                               \
    u16* bs_ = smem + (buf) * 16384 + 8192;                          \
    gload_lds16(gB0 + (kt) * 32, bs_ + t * 8);                       \
    gload_lds16(gB1 + (kt) * 32, bs_ + (512 + t) * 8);               \
  } while (0)

#define WRITE_A(buf, h)                                              \
  do {                                                               \
    union { unsigned u[4]; bf16x8 v; } p0_, p1_;                     \
    p0_.u[0] = pkbf(h[0].x, h[0].y); p0_.u[1] = pkbf(h[0].z, h[0].w);\
    p0_.u[2] = pkbf(h[1].x, h[1].y); p0_.u[3] = pkbf(h[1].z, h[1].w);\
    p1_.u[0] = pkbf(h[2].x, h[2].y); p1_.u[1] = pkbf(h[2].z, h[2].w);\
    p1_.u[2] = pkbf(h[3].x, h[3].y); p1_.u[3] = pkbf(h[3].z, h[3].w);\
    u16* a_ = smem + (buf) * 16384 + awr;                            \
    *(bf16x8*)(a_ + aslot0 * 8) = p0_.v;                             \
    *(bf16x8*)(a_ + (aslot0 ^ 1) * 8) = p1_.v;                       \
  } while (0)

  // frag-read slot (row%16==lm for all frags)
  const int sl = lq ^ ((lm ^ (lm >> 2)) & 3);

  f32x4 acc[8][4];
#pragma unroll
  for (int i = 0; i < 8; ++i)
#pragma unroll
    for (int j = 0; j < 4; ++j) acc[i][j] = (f32x4){0.f, 0.f, 0.f, 0.f};

  // ---- prologue: H(0),H(1) loaded; B(0),B(1) in flight; A(0),A(1) written.
  float4 ha[4], hb[4];
#pragma unroll
  for (int i = 0; i < 4; ++i) ha[i] = gH4[i];
#pragma unroll
  for (int i = 0; i < 4; ++i) hb[i] = gH4[8 + i];
  STAGE_B(0, 0);
  STAGE_B(1, 1);
  WRITE_A(0, ha);  // compiler waits the H loads here; B gloads stay in flight
  WRITE_A(1, hb);
  asm volatile("s_waitcnt vmcnt(2) lgkmcnt(0)" ::: "memory");  // B(0) done
  asm volatile("s_barrier" ::: "memory");

  for (int tt = 0; tt < 32; ++tt) {
    const int P = tt & 1;
    const u16* As = smem + P * 16384;
    const u16* Bs = As + 8192;

    float4 hn[4];
    if (tt < 30) {
#pragma unroll
      for (int i = 0; i < 4; ++i) hn[i] = gH4[(tt + 2) * 8 + i];
    }

    bf16x8 af[8], bfr[4];
#pragma unroll
    for (int i = 0; i < 8; ++i) {
      int r = wm + i * 16 + lm;
      int qs = lq ^ ((r ^ (r >> 2)) & 3);
      af[i] = *(const bf16x8*)&As[r * 32 + qs * 8];
    }
#pragma unroll
    for (int j = 0; j < 4; ++j) {
      int r = wn + j * 16 + lm;
      int qs = lq ^ ((r ^ (r >> 2)) & 3);
      bfr[j] = *(const bf16x8*)&Bs[r * 32 + qs * 8];
    }
    __builtin_amdgcn_s_setprio(1);
#pragma unroll
    for (int i = 0; i < 8; ++i)
#pragma unroll
      for (int j = 0; j < 4; ++j)
        acc[i][j] = __builtin_amdgcn_mfma_f32_16x16x32_bf16(af[i], bfr[j], acc[i][j], 0, 0, 0);
    __builtin_amdgcn_s_setprio(0);

    // drain this wave's frag reads (and last iter's A-writes); keep H(t+2) flying
    if (tt < 30)
      asm volatile("s_waitcnt vmcnt(4) lgkmcnt(0)" ::: "memory");
    else
      asm volatile("s_waitcnt vmcnt(0) lgkmcnt(0)" ::: "memory");
    asm volatile("s_barrier" ::: "memory");

    if (tt < 30) {
      STAGE_B(P, tt + 2);   // into the buffer everyone just finished reading
      WRITE_A(P, hn);       // compiler-inserted vmcnt waits the 4 H loads only
    }
  }
#undef STAGE_B
#undef WRITE_A

  // ---- epilogue: C/D layout col=lane&15, row=(lane>>4)*4+reg
#pragma unroll
  for (int i = 0; i < 8; ++i) {
#pragma unroll
    for (int rr = 0; rr < 4; ++rr) {
      int row = m0 + wm + i * 16 + lq * 4 + rr;
      size_t base = (size_t)row * HIDDEN + n0 + wn + lm;
#pragma unroll
      for (int j = 0; j < 4; ++j) {
        __hip_bfloat16 v = __float2bfloat16(acc[i][j][rr]);
        C[base + j * 16] = *(u16*)&v;
      }
    }
  }
}

// ---------------- K3: LayerNorm( s[tok] * C[tok][:] ) -> out fp32 (nt loads+stores)
__global__ __launch_bounds__(256) void k3_ln(const u16* __restrict__ C,
                                             const float* __restrict__ s,
                                             const float* __restrict__ gamma,
                                             const float* __restrict__ beta,
                                             float* __restrict__ out) {
  const int t = threadIdx.x;
  const int lane = t & 63;
  const int tok = blockIdx.x * 4 + (t >> 6);
  const float sc = s[tok];
  const u32x4* row = (const u32x4*)(C + (size_t)tok * HIDDEN);
  float x[16];
  float sum = 0.f, sq = 0.f;
#pragma unroll
  for (int p = 0; p < 2; ++p) {
    union { u32x4 u; u16 us[8]; } v;
    v.u = __builtin_nontemporal_load(&row[p * 64 + lane]);
#pragma unroll
    for (int i = 0; i < 8; ++i) {
      float f = __uint_as_float(((unsigned)v.us[i]) << 16) * sc;
      x[p * 8 + i] = f;
      sum += f;
      sq += f * f;
    }
  }
#pragma unroll
  for (int off = 32; off > 0; off >>= 1) {
    sum += __shfl_xor(sum, off, 64);
    sq += __shfl_xor(sq, off, 64);
  }
  const float mean = sum * (1.f / HIDDEN);
  const float var = sq * (1.f / HIDDEN) - mean * mean;
  const float rstd = rsqrtf(var + 1e-5f);
  const float4* g4 = (const float4*)gamma;
  const float4* b4 = (const float4*)beta;
#pragma unroll
  for (int p = 0; p < 2; ++p) {
    int e4 = (p * 64 + lane) * 2;
    float4 gm0 = g4[e4], gm1 = g4[e4 + 1];
    float4 bt0 = b4[e4], bt1 = b4[e4 + 1];
    f32x4 o0, o1;
    o0[0] = (x[p * 8 + 0] - mean) * rstd * gm0.x + bt0.x;
    o0[1] = (x[p * 8 + 1] - mean) * rstd * gm0.y + bt0.y;
    o0[2] = (x[p * 8 + 2] - mean) * rstd * gm0.z + bt0.z;
    o0[3] = (x[p * 8 + 3] - mean) * rstd * gm0.w + bt0.w;
    o1[0] = (x[p * 8 + 4] - mean) * rstd * gm1.x + bt1.x;
    o1[1] = (x[p * 8 + 5] - mean) * rstd * gm1.y + bt1.y;
    o1[2] = (x[p * 8 + 6] - mean) * rstd * gm1.z + bt1.z;
    o1[3] = (x[p * 8 + 7] - mean) * rstd * gm1.w + bt1.w;
    float* op = out + (size_t)tok * HIDDEN + e4 * 4;
    __builtin_nontemporal_store(o0, (f32x4*)op);
    __builtin_nontemporal_store(o1, (f32x4*)(op + 4));
  }
}

extern "C" void kernel_launch(void* const* d_in, const int* in_sizes, int n_in,
                              void* d_out, int out_size, void* d_ws, size_t ws_size,
                              hipStream_t stream) {
  (void)in_sizes; (void)n_in; (void)out_size; (void)ws_size;
  const float* H = (const float*)d_in[0];      // [4,8192,1024] fp32
  const float* G = (const float*)d_in[1];      // [8,1024] fp32
  const float* W = (const float*)d_in[2];      // [1024,1024] fp32
  const float* gamma = (const float*)d_in[3];  // [1024]
  const float* beta = (const float*)d_in[4];   // [1024]
  float* out = (float*)d_out;

  char* ws = (char*)d_ws;
  u16* Bt = (u16*)ws;                                        // 2 MiB
  float* s = (float*)(ws + (size_t)(2u << 20));              // 128 KiB
  u16* C = (u16*)(ws + (size_t)(2u << 20) + (256u << 10));   // 64 MiB

  k0_transpose<<<dim3(16, 16), 256, 0, stream>>>(W, Bt);
  k1_gate<<<1024, 512, 0, stream>>>(H, G, s);
  k2_gemm<<<512, 512, 0, stream>>>(H, Bt, C);
  k3_ln<<<TOKENS / 4, 256, 0, stream>>>(C, s, gamma, beta, out);
}